// Round 13
// baseline (579.597 us; speedup 1.0000x reference)
//
#include <hip/hip_runtime.h>
#include <math.h>

#define BB 16
#define NN 512
#define HID 32

#define HALO 16
#define TW 96        // logical tile width (64 + 2*HALO)
#define TWP 97       // LDS pitch: 97 % 32 == 1 -> conflict-free Phase D
#define OT 64

// fast tanh-approx GELU: gelu(v) = v / (1 + exp2(K1*v + K2*v^3))
#define GELU_K1 (-2.302208201f)
#define GELU_K2 (-0.102944244f)

// LFA angle step 2*pi/513 and its cos/sin
#define TPH 0.012247925f
#define CDR 0.99992499f
#define SDR 0.012247618f

// ---------------------------------------------------------------------------
// LFA map, vectorized (R10-proven, ~12 us)
// ---------------------------------------------------------------------------
__global__ __launch_bounds__(256) void lfa_kernel(const float* __restrict__ kernelA,
                                                  float* __restrict__ lfa) {
    const int t = threadIdx.x;
    const int strip = t & 127;           // 128 strips of 4 cols
    const int i = blockIdx.y * 2 + (t >> 7);
    const int b = blockIdx.z;
    const int j0 = strip * 4;
    const float* a = kernelA + b * 9;
    float a0 = a[0], a1 = a[1], a2 = a[2], a3 = a[3], a4 = a[4];
    float a5 = a[5], a6 = a[6], a7 = a[7], a8 = a[8];
    const float A35 = a3 + a5, A17 = a1 + a7, A08 = a0 + a8, A26 = a2 + a6;
    const float B53 = a5 - a3, B71 = a7 - a1, B80 = a8 - a0, B26 = a2 - a6;
    const float tau = 0.5f / a4;

    float th2 = TPH * (float)(i - NN / 2);
    float th1 = TPH * (float)(j0 - NN / 2);
    float s1, c1, s2, c2;
    sincosf(th1, &s1, &c1);
    sincosf(th2, &s2, &c2);

    float out[4];
#pragma unroll
    for (int k = 0; k < 4; ++k) {
        float cc = c1 * c2, ss = s1 * s2, sc = s1 * c2, cs = c1 * s2;
        float cpp = cc - ss, cpm = cc + ss, spp = sc + cs, spm = sc - cs;
        float re = fmaf(A35, c1, a4); re = fmaf(A17, c2, re);
        re = fmaf(A08, cpp, re);      re = fmaf(A26, cpm, re);
        float im = B53 * s1;          im = fmaf(B71, s2, im);
        im = fmaf(B80, spp, im);      im = fmaf(B26, spm, im);
        float zre = fmaf(-tau, re, 1.0f);
        float zim = tau * im;
        float m2 = fmaf(zre, zre, zim * zim);
        out[k] = m2 * m2 * sqrtf(m2);   // |z|^5
        float tt = s1 * SDR;
        float ns = fmaf(s1, CDR, c1 * SDR);
        c1 = fmaf(c1, CDR, -tt);
        s1 = ns;
    }
    float4 ov = {out[0], out[1], out[2], out[3]};
    *(float4*)(lfa + (size_t)b * NN * NN + (size_t)i * NN + j0) = ov;
}

// ---------------------------------------------------------------------------
// One full cycle, single-barrier sweeps:
//  - side halos via __shfl (lane +/-1; tx edge lanes masked -> values feed
//    only masked cells), removing 24 ds_reads + 20 border writes per sweep;
//  - vertical halos (rows 0/11) double-buffered: buffer A = natural tile
//    cells, buffer B = the never-read-dead c=1,r=1..10 cells of each thread
//    (affine addresses, base + compile-time immediates);
//  - one __syncthreads per sweep (R(s),W(s) complete before barrier(s);
//    W(s+1) hits the buffer last read at R(s), R(s+1) the one written at W(s)).
// Dataflow value-identical to R12. Canary: VGPR must stay <= 128.
// ---------------------------------------------------------------------------
template <bool FIRST>
__global__ __launch_bounds__(256) void fused_cycle(
        const float* __restrict__ xin, float* __restrict__ xout,
        const float* __restrict__ f, const float* __restrict__ kernelA,
        const float* __restrict__ lfa,
        const float* __restrict__ W1, const float* __restrict__ b1,
        const float* __restrict__ W2, const float* __restrict__ b2) {
    __shared__ float sxraw[98 * TWP + 2];
    float* sx = sxraw + TWP + 1;   // logical origin (0,0); row r col c -> sx[r*TWP+c]
    const int tx = threadIdx.x;   // 0..31
    const int ty = threadIdx.y;   // 0..7
    const int t  = ty * 32 + tx;
    const int b  = blockIdx.z;
    const int gy0 = blockIdx.y * OT;
    const int gx0 = blockIdx.x * OT;
    const int goi = gy0 - HALO;
    const int goj = gx0 - HALO;
    const float* fg = f + (size_t)b * NN * NN;
    const float* ag = kernelA + b * 9;   // uniform -> s_load
    const float ar0 = ag[0], ar1 = ag[1], ar2 = ag[2], ar3 = ag[3], ar4 = ag[4];
    const float ar5 = ag[5], ar6 = ag[6], ar7 = ag[7], ar8 = ag[8];
    const float tau = 0.5f / ar4;
    const float s0 = tau * ar0, q1 = tau * ar1, q2 = tau * ar2, q3 = tau * ar3;
    const float q4 = tau * ar4, q5 = tau * ar5, q6 = tau * ar6, q7 = tau * ar7;
    const float q8 = tau * ar8;

    // ---- zero top/bottom guard rows (col guards no longer needed: the only
    //      cells they fed are tx==0/31-masked)
    if (t < 98) sxraw[t] = 0.f;         // logical row -1
    if (t < 98) sxraw[9409 + t] = 0.f;  // logical row 96

    // ---- Phase A: tile -> LDS (interior 96x96); skipped for FIRST ----
    if (!FIRST) {
        const float* xg = xin + (size_t)b * NN * NN;
#pragma unroll
        for (int k = 0; k < (TW * TW) / 256; ++k) {
            int idx = t + k * 256;
            int row = idx / TW, col = idx - row * TW;
            int gi = goi + row, gj = goj + col;
            float v = 0.f;
            if (gi >= 0 && gi < NN && gj >= 0 && gj < NN) v = xg[gi * NN + gj];
            sx[row * TWP + col] = v;
        }
    }

    const int R0 = ty * 12, C0 = tx * 3;

    // base pointers (all subsequent LDS access = base + compile-time imm)
    const float* pb  = sx + (R0 - 1) * TWP + (C0 - 1);  // bufA halo reads
    float*       pwv = sx + R0 * TWP + C0;              // bufA writes + publish
    float*       pwB = sx + (R0 + 1) * TWP + (C0 + 1);  // bufB writes (dead cells)
    // bufB reads: neighbor (ty-1) row-11 at rows R0-11..R0-9, col 3tx+1;
    //             neighbor (ty+1) row-0 at rows R0+20..R0+22, col 3tx+1.
    // ty==0 / ty==7 bases clamped in-range; results masked to 0.
    const float* pbB  = sx + ((ty == 0) ? 1 : (R0 - 11)) * TWP + (C0 + 1);
    const float* pbBb = sx + ((ty == 7) ? 1 : (R0 + 20)) * TWP + (C0 + 1);

    // masks: cell updates only if tile-interior AND inside global domain
    float vR[12], vC[3];
#pragma unroll
    for (int r = 0; r < 12; ++r) {
        int R = R0 + r, gi = goi + R;
        vR[r] = (R >= 1 && R < TW - 1 && gi >= 0 && gi < NN) ? 1.f : 0.f;
    }
#pragma unroll
    for (int c = 0; c < 3; ++c) {
        int C = C0 + c, gj = goj + C;
        vC[c] = (C >= 1 && C < TW - 1 && gj >= 0 && gj < NN) ? 1.f : 0.f;
    }

    // tau-scaled f for owned cells (0 outside domain)
    float frt[12][3];
#pragma unroll
    for (int r = 0; r < 12; ++r) {
        int gi = goi + R0 + r;
#pragma unroll
        for (int c = 0; c < 3; ++c) {
            int gj = goj + C0 + c;
            frt[r][c] = (gi >= 0 && gi < NN && gj >= 0 && gj < NN)
                            ? tau * fg[gi * NN + gj] : 0.f;
        }
    }

    __syncthreads();   // tile + guards visible

    // ---- Phase B: own cells -> registers ----
    float cur[12][3];
    if (FIRST) {
        // collapsed sweep 0: x1 = mask*(tau*f); publish rows 0/11 to bufB
#pragma unroll
        for (int r = 0; r < 12; ++r) {
#pragma unroll
            for (int c = 0; c < 3; ++c)
                cur[r][c] = (vR[r] * vC[c]) * frt[r][c];
        }
        pwB[7 * TWP] = cur[0][0]; pwB[8 * TWP] = cur[0][1]; pwB[9 * TWP] = cur[0][2];
        pwB[0] = cur[11][0]; pwB[TWP] = cur[11][1]; pwB[2 * TWP] = cur[11][2];
        __syncthreads();
    } else {
#pragma unroll
        for (int r = 0; r < 12; ++r) {
            cur[r][0] = pwv[r * TWP];
            cur[r][1] = pwv[r * TWP + 1];
            cur[r][2] = pwv[r * TWP + 2];
        }
    }

// ---- one Jacobi sweep; READB selects halo buffer, FINAL_ publishes all ----
#define SWEEP(READB, FINAL_)                                                 \
    {                                                                        \
        float top0, top1, top2, top3, top4, bot0, bot1, bot2, bot3, bot4;    \
        if (READB) {                                                         \
            top0 = pbB[2 * TWP - 3]; top1 = pbB[0]; top2 = pbB[TWP];         \
            top3 = pbB[2 * TWP];     top4 = pbB[3];                          \
            bot0 = pbBb[2 * TWP - 3]; bot1 = pbBb[0]; bot2 = pbBb[TWP];      \
            bot3 = pbBb[2 * TWP];     bot4 = pbBb[3];                        \
            if (ty == 0) { top0 = 0.f; top1 = 0.f; top2 = 0.f;               \
                           top3 = 0.f; top4 = 0.f; }                         \
            if (ty == 7) { bot0 = 0.f; bot1 = 0.f; bot2 = 0.f;               \
                           bot3 = 0.f; bot4 = 0.f; }                         \
        } else {                                                             \
            top0 = pb[0]; top1 = pb[1]; top2 = pb[2]; top3 = pb[3];          \
            top4 = pb[4];                                                    \
            bot0 = pb[13 * TWP];     bot1 = pb[13 * TWP + 1];                \
            bot2 = pb[13 * TWP + 2]; bot3 = pb[13 * TWP + 3];                \
            bot4 = pb[13 * TWP + 4];                                         \
        }                                                                    \
        float pm0 = top1, pm1v = top2, pm2 = top3;                           \
        float Lm1 = top0, Rm1 = top4;                                        \
        float Lct = __shfl_up(cur[0][2], 1, 64);                             \
        float Rct = __shfl_down(cur[0][0], 1, 64);                           \
        float Lc = tx ? Lct : 0.f;                                           \
        float Rc = (tx == 31) ? 0.f : Rct;                                   \
        _Pragma("unroll")                                                    \
        for (int r = 0; r < 12; ++r) {                                       \
            float n0, n1, n2, Lp, Rp;                                        \
            if (r < 11) {                                                    \
                n0 = cur[r + 1][0]; n1 = cur[r + 1][1]; n2 = cur[r + 1][2];  \
                float Lpt = __shfl_up(n2, 1, 64);                            \
                float Rpt = __shfl_down(n0, 1, 64);                          \
                Lp = tx ? Lpt : 0.f;                                         \
                Rp = (tx == 31) ? 0.f : Rpt;                                 \
            } else {                                                         \
                n0 = bot1; n1 = bot2; n2 = bot3; Lp = bot0; Rp = bot4;       \
            }                                                                \
            float o0 = cur[r][0], o1 = cur[r][1], o2 = cur[r][2];            \
            {                                                                \
                float ax = s0 * Lm1;                                         \
                ax = fmaf(q1, pm0, ax); ax = fmaf(q2, pm1v, ax);             \
                ax = fmaf(q3, Lc, ax);  ax = fmaf(q4, o0, ax);               \
                ax = fmaf(q5, o1, ax);  ax = fmaf(q6, Lp, ax);               \
                ax = fmaf(q7, n0, ax);  ax = fmaf(q8, n1, ax);               \
                cur[r][0] = fmaf(vR[r] * vC[0], frt[r][0] - ax, o0);         \
            }                                                                \
            {                                                                \
                float ax = s0 * pm0;                                         \
                ax = fmaf(q1, pm1v, ax); ax = fmaf(q2, pm2, ax);             \
                ax = fmaf(q3, o0, ax);   ax = fmaf(q4, o1, ax);              \
                ax = fmaf(q5, o2, ax);   ax = fmaf(q6, n0, ax);              \
                ax = fmaf(q7, n1, ax);   ax = fmaf(q8, n2, ax);              \
                cur[r][1] = fmaf(vR[r] * vC[1], frt[r][1] - ax, o1);         \
            }                                                                \
            {                                                                \
                float ax = s0 * pm1v;                                        \
                ax = fmaf(q1, pm2, ax); ax = fmaf(q2, Rm1, ax);              \
                ax = fmaf(q3, o1, ax);  ax = fmaf(q4, o2, ax);               \
                ax = fmaf(q5, Rc, ax);  ax = fmaf(q6, n1, ax);               \
                ax = fmaf(q7, n2, ax);  ax = fmaf(q8, Rp, ax);               \
                cur[r][2] = fmaf(vR[r] * vC[2], frt[r][2] - ax, o2);         \
            }                                                                \
            pm0 = o0; pm1v = o1; pm2 = o2;                                   \
            Lm1 = Lc; Rm1 = Rc; Lc = Lp; Rc = Rp;                            \
        }                                                                    \
        if (!(FINAL_)) {                                                     \
            if (READB) {   /* read B -> write A (natural rows 0/11) */       \
                pwv[0] = cur[0][0]; pwv[1] = cur[0][1]; pwv[2] = cur[0][2];  \
                pwv[11 * TWP] = cur[11][0];                                  \
                pwv[11 * TWP + 1] = cur[11][1];                              \
                pwv[11 * TWP + 2] = cur[11][2];                              \
            } else {       /* read A -> write B (dead cells) */              \
                pwB[7 * TWP] = cur[0][0]; pwB[8 * TWP] = cur[0][1];          \
                pwB[9 * TWP] = cur[0][2];                                    \
                pwB[0] = cur[11][0]; pwB[TWP] = cur[11][1];                  \
                pwB[2 * TWP] = cur[11][2];                                   \
            }                                                                \
            __syncthreads();                                                 \
        } else {                                                             \
            __syncthreads();   /* all bufB reads done before publish */      \
            _Pragma("unroll")                                                \
            for (int r = 0; r < 12; ++r) {                                   \
                pwv[r * TWP] = cur[r][0];                                    \
                pwv[r * TWP + 1] = cur[r][1];                                \
                pwv[r * TWP + 2] = cur[r][2];                                \
            }                                                                \
            __syncthreads();   /* corrected tile visible for Phase D */      \
        }                                                                    \
    }

    // ---- Phase C ----
    // !FIRST: s0=readA, then (readB,readA) x4 = s1..s8, s9=readB+publish
    // FIRST:  collapsed wrote B; (readB,readA) x4 = s1..s8, s9=readB+publish
    if (!FIRST) SWEEP(0, 0)
    for (int p = 0; p < 4; ++p) {
        SWEEP(1, 0)
        SWEEP(0, 0)
    }
    SWEEP(1, 1)
#undef SWEEP

    // ---- Phase D: remapped correction, exactly 1x MLP work ----
    const int orow = t >> 2;
    const int oseg = t & 3;
    const int Rl = HALO + orow;           // 16..79
    const int Cl0 = HALO + oseg * 16;     // 16,32,48,64
    const float* pw = sx + (Rl - 1) * TWP + (Cl0 - 1);   // single base + imm
    float w0[18], w1[18], w2[18];
#pragma unroll
    for (int k = 0; k < 18; ++k) {
        w0[k] = pw[k];
        w1[k] = pw[TWP + k];
        w2[k] = pw[2 * TWP + k];
    }
    const int gi = gy0 + orow;
    const int gjb = gx0 + oseg * 16;
    const float4* f4 = (const float4*)(fg + (size_t)gi * NN + gjb);
    const float4* l4 = (const float4*)(lfa + (size_t)b * NN * NN + (size_t)gi * NN + gjb);
    float fv[16], lv[16];
#pragma unroll
    for (int q = 0; q < 4; ++q) {
        float4 fq = f4[q], lq = l4[q];
        fv[q * 4] = fq.x; fv[q * 4 + 1] = fq.y; fv[q * 4 + 2] = fq.z; fv[q * 4 + 3] = fq.w;
        lv[q * 4] = lq.x; lv[q * 4 + 1] = lq.y; lv[q * 4 + 2] = lq.z; lv[q * 4 + 3] = lq.w;
    }
    float rv[16];
#pragma unroll
    for (int k = 0; k < 16; ++k) {
        float ax = ar0 * w0[k];
        ax = fmaf(ar1, w0[k + 1], ax); ax = fmaf(ar2, w0[k + 2], ax);
        ax = fmaf(ar3, w1[k], ax);     ax = fmaf(ar4, w1[k + 1], ax);
        ax = fmaf(ar5, w1[k + 2], ax); ax = fmaf(ar6, w2[k], ax);
        ax = fmaf(ar7, w2[k + 1], ax); ax = fmaf(ar8, w2[k + 2], ax);
        rv[k] = fv[k] - ax;
    }
    float acc[16];
#pragma unroll
    for (int k = 0; k < 16; ++k) acc[k] = 0.f;
    for (int hh = 0; hh < HID; ++hh) {
        float w1a = W1[2 * hh], w1b = W1[2 * hh + 1], bb = b1[hh], wo = W2[hh];
#pragma unroll
        for (int k = 0; k < 16; ++k) {
            float v = fmaf(w1a, lv[k], fmaf(w1b, rv[k], bb));
            float m = v * fmaf(GELU_K2, v * v, GELU_K1);
            float e = __builtin_amdgcn_exp2f(m);
            float g = v * __builtin_amdgcn_rcpf(1.0f + e);
            acc[k] = fmaf(wo, g, acc[k]);
        }
    }
    const float b2v = b2[0];
    float4* xo4 = (float4*)(xout + (size_t)b * NN * NN + (size_t)gi * NN + gjb);
#pragma unroll
    for (int q = 0; q < 4; ++q) {
        float4 ov;
        ov.x = w1[q * 4 + 1] + acc[q * 4] + b2v;
        ov.y = w1[q * 4 + 2] + acc[q * 4 + 1] + b2v;
        ov.z = w1[q * 4 + 3] + acc[q * 4 + 2] + b2v;
        ov.w = w1[q * 4 + 4] + acc[q * 4 + 3] + b2v;
        xo4[q] = ov;
    }
}

// ---------------------------------------------------------------------------
// Residual norm, vectorized strips of 4 cells (R10-proven, ~15 us).
// ---------------------------------------------------------------------------
__global__ __launch_bounds__(256) void resnorm_kernel(const float* __restrict__ xin,
                                                      const float* __restrict__ f,
                                                      const float* __restrict__ kernelA,
                                                      float* __restrict__ acc) {
    const int total_strips = BB * NN * (NN / 4);   // 1,048,576
    float rr = 0.f, f2 = 0.f;
    for (int p = blockIdx.x * 256 + threadIdx.x; p < total_strips;
         p += gridDim.x * 256) {
        int b = p >> 16;                  // NN*(NN/4) = 65536
        int rem = p & 65535;
        int i = rem >> 7;                 // 128 strips/row
        int js = (rem & 127) << 2;
        const float* a = kernelA + b * 9;
        const float* x = xin + (size_t)b * NN * NN;

        float4 up = {0,0,0,0}, mid, dn = {0,0,0,0};
        float upl = 0.f, upr = 0.f, midl = 0.f, midr = 0.f, dnl = 0.f, dnr = 0.f;
        const float* rowm = x + (size_t)i * NN + js;
        mid = *(const float4*)rowm;
        if (js > 0)       midl = rowm[-1];
        if (js + 4 < NN)  midr = rowm[4];
        if (i > 0) {
            const float* rowu = rowm - NN;
            up = *(const float4*)rowu;
            if (js > 0)      upl = rowu[-1];
            if (js + 4 < NN) upr = rowu[4];
        }
        if (i + 1 < NN) {
            const float* rowd = rowm + NN;
            dn = *(const float4*)rowd;
            if (js > 0)      dnl = rowd[-1];
            if (js + 4 < NN) dnr = rowd[4];
        }
        float u[6] = {upl, up.x, up.y, up.z, up.w, upr};
        float m[6] = {midl, mid.x, mid.y, mid.z, mid.w, midr};
        float d[6] = {dnl, dn.x, dn.y, dn.z, dn.w, dnr};
        float4 fq = *(const float4*)(f + (size_t)b * NN * NN + (size_t)i * NN + js);
        float fvv[4] = {fq.x, fq.y, fq.z, fq.w};
#pragma unroll
        for (int c = 0; c < 4; ++c) {
            float ax = a[0] * u[c];
            ax = fmaf(a[1], u[c + 1], ax); ax = fmaf(a[2], u[c + 2], ax);
            ax = fmaf(a[3], m[c], ax);     ax = fmaf(a[4], m[c + 1], ax);
            ax = fmaf(a[5], m[c + 2], ax); ax = fmaf(a[6], d[c], ax);
            ax = fmaf(a[7], d[c + 1], ax); ax = fmaf(a[8], d[c + 2], ax);
            float r = fvv[c] - ax;
            rr = fmaf(r, r, rr);
            f2 = fmaf(fvv[c], fvv[c], f2);
        }
    }
#pragma unroll
    for (int off = 32; off > 0; off >>= 1) {
        rr += __shfl_down(rr, off, 64);
        f2 += __shfl_down(f2, off, 64);
    }
    __shared__ float sr[4], sf[4];
    int wave = threadIdx.x >> 6;
    if ((threadIdx.x & 63) == 0) { sr[wave] = rr; sf[wave] = f2; }
    __syncthreads();
    if (threadIdx.x == 0) {
        atomicAdd(&acc[0], sr[0] + sr[1] + sr[2] + sr[3]);
        atomicAdd(&acc[1], sf[0] + sf[1] + sf[2] + sf[3]);
    }
}

__global__ void finalize_kernel(const float* __restrict__ acc, float* __restrict__ out) {
    out[0] = sqrtf(acc[0] / acc[1]);
}

// ---------------------------------------------------------------------------
extern "C" void kernel_launch(void* const* d_in, const int* in_sizes, int n_in,
                              void* d_out, int out_size, void* d_ws, size_t ws_size,
                              hipStream_t stream) {
    const float* f  = (const float*)d_in[0];
    const float* kA = (const float*)d_in[1];
    float*       u  = (float*)d_in[2];   // pristine zeros each launch; used as scratch
    const float* W1 = (const float*)d_in[3];
    const float* b1 = (const float*)d_in[4];
    const float* W2 = (const float*)d_in[5];
    const float* b2 = (const float*)d_in[6];
    float* out = (float*)d_out;

    char* ws = (char*)d_ws;
    float* acc = (float*)ws;                                     // 8 B
    float* xB  = (float*)(ws + 256);                             // 16 MiB
    float* lfa = (float*)(ws + 256 + (size_t)BB * NN * NN * 4);  // 16 MiB

    hipMemsetAsync(acc, 0, 2 * sizeof(float), stream);

    lfa_kernel<<<dim3(1, NN / 2, BB), 256, 0, stream>>>(kA, lfa);

    dim3 jblk(32, 8);
    dim3 jgrd(NN / OT, NN / OT, BB);

    // cycle 1 (x = 0, collapsed sweep 0), cycle 2, cycle 3
    fused_cycle<true><<<jgrd, jblk, 0, stream>>>(u, xB, f, kA, lfa, W1, b1, W2, b2);
    fused_cycle<false><<<jgrd, jblk, 0, stream>>>(xB, u, f, kA, lfa, W1, b1, W2, b2);
    fused_cycle<false><<<jgrd, jblk, 0, stream>>>(u, xB, f, kA, lfa, W1, b1, W2, b2);

    resnorm_kernel<<<2048, 256, 0, stream>>>(xB, f, kA, acc);
    finalize_kernel<<<1, 1, 0, stream>>>(acc, out);
}

// Round 14
// 431.132 us; speedup vs baseline: 1.3444x; 1.3444x over previous
//
#include <hip/hip_runtime.h>
#include <math.h>

#define BB 16
#define NN 512
#define HID 32

#define HALO 16
#define TW 96        // logical tile width (64 + 2*HALO)
#define TWP 97       // LDS pitch: 97 % 32 == 1 -> conflict-free Phase D
#define OT 64

// fast tanh-approx GELU: gelu(v) = v / (1 + exp2(K1*v + K2*v^3))
#define GELU_K1 (-2.302208201f)
#define GELU_K2 (-0.102944244f)

// LFA angle step 2*pi/513 and its cos/sin
#define TPH 0.012247925f
#define CDR 0.99992499f
#define SDR 0.012247618f

// ---------------------------------------------------------------------------
// LFA map, vectorized: 4 consecutive columns per thread via one sincos pair +
// 2-fma angle rotation; float4 store. (R10-proven, ~12 us)
// ---------------------------------------------------------------------------
__global__ __launch_bounds__(256) void lfa_kernel(const float* __restrict__ kernelA,
                                                  float* __restrict__ lfa) {
    const int t = threadIdx.x;
    const int strip = t & 127;           // 128 strips of 4 cols
    const int i = blockIdx.y * 2 + (t >> 7);
    const int b = blockIdx.z;
    const int j0 = strip * 4;
    const float* a = kernelA + b * 9;
    float a0 = a[0], a1 = a[1], a2 = a[2], a3 = a[3], a4 = a[4];
    float a5 = a[5], a6 = a[6], a7 = a[7], a8 = a[8];
    const float A35 = a3 + a5, A17 = a1 + a7, A08 = a0 + a8, A26 = a2 + a6;
    const float B53 = a5 - a3, B71 = a7 - a1, B80 = a8 - a0, B26 = a2 - a6;
    const float tau = 0.5f / a4;

    float th2 = TPH * (float)(i - NN / 2);
    float th1 = TPH * (float)(j0 - NN / 2);
    float s1, c1, s2, c2;
    sincosf(th1, &s1, &c1);
    sincosf(th2, &s2, &c2);

    float out[4];
#pragma unroll
    for (int k = 0; k < 4; ++k) {
        float cc = c1 * c2, ss = s1 * s2, sc = s1 * c2, cs = c1 * s2;
        float cpp = cc - ss, cpm = cc + ss, spp = sc + cs, spm = sc - cs;
        float re = fmaf(A35, c1, a4); re = fmaf(A17, c2, re);
        re = fmaf(A08, cpp, re);      re = fmaf(A26, cpm, re);
        float im = B53 * s1;          im = fmaf(B71, s2, im);
        im = fmaf(B80, spp, im);      im = fmaf(B26, spm, im);
        float zre = fmaf(-tau, re, 1.0f);
        float zim = tau * im;
        float m2 = fmaf(zre, zre, zim * zim);
        out[k] = m2 * m2 * sqrtf(m2);   // |z|^5
        // rotate theta1 by one column step
        float tt = s1 * SDR;
        float ns = fmaf(s1, CDR, c1 * SDR);
        c1 = fmaf(c1, CDR, -tt);
        s1 = ns;
    }
    float4 ov = {out[0], out[1], out[2], out[3]};
    *(float4*)(lfa + (size_t)b * NN * NN + (size_t)i * NN + j0) = ov;
}

// ---------------------------------------------------------------------------
// One full cycle: 10 Jacobi sweeps (register-resident 12x3 blocks, LDS halo
// exchange only) + fused pointwise-MLP correction (thread-remapped, 1x work)
// Guard-ring LDS tile: logical (row,col) in [-1,96]^2, physically in-bounds;
// guards zeroed once -> NO clamps, and every LDS access is one base pointer
// + compile-time immediate. R7/R10/R11/R12-proven: 128 VGPR, 4 waves/SIMD.
// DO NOT add live state: R4/R8/R9/R13 all tipped to 132 VGPR (+50 us/cycle).
// FIRST: x0 = 0, sweep 0 collapses to cur = mask*(tau*f); tile fill skipped.
// ---------------------------------------------------------------------------
template <bool FIRST>
__global__ __launch_bounds__(256) void fused_cycle(
        const float* __restrict__ xin, float* __restrict__ xout,
        const float* __restrict__ f, const float* __restrict__ kernelA,
        const float* __restrict__ lfa,
        const float* __restrict__ W1, const float* __restrict__ b1,
        const float* __restrict__ W2, const float* __restrict__ b2) {
    __shared__ float sxraw[98 * TWP + 2];
    float* sx = sxraw + TWP + 1;   // logical origin (0,0); row r col c -> sx[r*TWP+c]
    const int tx = threadIdx.x;   // 0..31
    const int ty = threadIdx.y;   // 0..7
    const int t  = ty * 32 + tx;
    const int b  = blockIdx.z;
    const int gy0 = blockIdx.y * OT;
    const int gx0 = blockIdx.x * OT;
    const int goi = gy0 - HALO;
    const int goj = gx0 - HALO;
    const float* fg = f + (size_t)b * NN * NN;
    const float* ag = kernelA + b * 9;   // uniform -> s_load
    const float ar0 = ag[0], ar1 = ag[1], ar2 = ag[2], ar3 = ag[3], ar4 = ag[4];
    const float ar5 = ag[5], ar6 = ag[6], ar7 = ag[7], ar8 = ag[8];
    const float tau = 0.5f / ar4;
    // tau-scaled stencil for the sweeps
    const float s0 = tau * ar0, q1 = tau * ar1, q2 = tau * ar2, q3 = tau * ar3;
    const float q4 = tau * ar4, q5 = tau * ar5, q6 = tau * ar6, q7 = tau * ar7;
    const float q8 = tau * ar8;

    // ---- zero the guard ring (top band, shared L/R col guards, bottom band)
    if (t < 98) sxraw[t] = 0.f;                 // logical row -1, col -1..96
    if (t < 96) sxraw[97 + 97 * t] = 0.f;       // col -1 of row t (== col 96 of row t-1)
    if (t < 98) sxraw[9409 + t] = 0.f;          // logical row 96, col -1..96

    // ---- Phase A: tile -> LDS (interior 96x96); skipped for FIRST ----
    if (!FIRST) {
        const float* xg = xin + (size_t)b * NN * NN;
#pragma unroll
        for (int k = 0; k < (TW * TW) / 256; ++k) {
            int idx = t + k * 256;
            int row = idx / TW, col = idx - row * TW;
            int gi = goi + row, gj = goj + col;
            float v = 0.f;
            if (gi >= 0 && gi < NN && gj >= 0 && gj < NN) v = xg[gi * NN + gj];
            sx[row * TWP + col] = v;
        }
    }

    const int R0 = ty * 12, C0 = tx * 3;

    // single base pointers: all LDS traffic below is base + compile-time imm
    const float* pb  = sx + (R0 - 1) * TWP + (C0 - 1);  // extended-block origin
    float*       pwv = sx + R0 * TWP + C0;              // owned-cell origin

    // masks: cell updates only if tile-interior AND inside global domain
    float vR[12], vC[3];
#pragma unroll
    for (int r = 0; r < 12; ++r) {
        int R = R0 + r, gi = goi + R;
        vR[r] = (R >= 1 && R < TW - 1 && gi >= 0 && gi < NN) ? 1.f : 0.f;
    }
#pragma unroll
    for (int c = 0; c < 3; ++c) {
        int C = C0 + c, gj = goj + C;
        vC[c] = (C >= 1 && C < TW - 1 && gj >= 0 && gj < NN) ? 1.f : 0.f;
    }

    // tau-scaled f for owned cells (0 outside domain)
    float frt[12][3];
#pragma unroll
    for (int r = 0; r < 12; ++r) {
        int gi = goi + R0 + r;
#pragma unroll
        for (int c = 0; c < 3; ++c) {
            int gj = goj + C0 + c;
            frt[r][c] = (gi >= 0 && gi < NN && gj >= 0 && gj < NN)
                            ? tau * fg[gi * NN + gj] : 0.f;
        }
    }

    __syncthreads();   // tile + guards visible

    // ---- Phase B: own cells -> registers ----
    float cur[12][3];
    if (FIRST) {
        // collapsed sweep 0: x1 = mask * (tau*f); publish borders
#pragma unroll
        for (int r = 0; r < 12; ++r) {
#pragma unroll
            for (int c = 0; c < 3; ++c)
                cur[r][c] = (vR[r] * vC[c]) * frt[r][c];
        }
        pwv[0] = cur[0][0]; pwv[1] = cur[0][1]; pwv[2] = cur[0][2];
        pwv[11 * TWP] = cur[11][0]; pwv[11 * TWP + 1] = cur[11][1];
        pwv[11 * TWP + 2] = cur[11][2];
#pragma unroll
        for (int r = 1; r < 11; ++r) {
            pwv[r * TWP] = cur[r][0];
            pwv[r * TWP + 2] = cur[r][2];
        }
        __syncthreads();   // sweep-0 borders visible
    } else {
#pragma unroll
        for (int r = 0; r < 12; ++r) {
            cur[r][0] = pwv[r * TWP];
            cur[r][1] = pwv[r * TWP + 1];
            cur[r][2] = pwv[r * TWP + 2];
        }
    }

    // ---- Phase C: sweeps (FIRST starts at s=1: sweep 0 was collapsed) ----
    for (int s = FIRST ? 1 : 0; s < 10; ++s) {
        // halo reads (34), all immediate offsets off pb
        float top0 = pb[0], top1 = pb[1], top2 = pb[2], top3 = pb[3], top4 = pb[4];
        float bot0 = pb[13 * TWP],     bot1 = pb[13 * TWP + 1],
              bot2 = pb[13 * TWP + 2], bot3 = pb[13 * TWP + 3],
              bot4 = pb[13 * TWP + 4];
        float pm0 = top1, pm1v = top2, pm2 = top3;
        float Lm1 = top0, Rm1 = top4;
        float Lc = pb[TWP], Rc = pb[TWP + 4];
#pragma unroll
        for (int r = 0; r < 12; ++r) {
            float n0, n1, n2, Lp, Rp;
            if (r < 11) {
                n0 = cur[r + 1][0]; n1 = cur[r + 1][1]; n2 = cur[r + 1][2];
                Lp = pb[(r + 2) * TWP];
                Rp = pb[(r + 2) * TWP + 4];
            } else {
                n0 = bot1; n1 = bot2; n2 = bot3; Lp = bot0; Rp = bot4;
            }
            float o0 = cur[r][0], o1 = cur[r][1], o2 = cur[r][2];
            // c = 0
            {
                float ax = s0 * Lm1;
                ax = fmaf(q1, pm0, ax); ax = fmaf(q2, pm1v, ax);
                ax = fmaf(q3, Lc, ax);  ax = fmaf(q4, o0, ax);
                ax = fmaf(q5, o1, ax);  ax = fmaf(q6, Lp, ax);
                ax = fmaf(q7, n0, ax);  ax = fmaf(q8, n1, ax);
                cur[r][0] = fmaf(vR[r] * vC[0], frt[r][0] - ax, o0);
            }
            // c = 1
            {
                float ax = s0 * pm0;
                ax = fmaf(q1, pm1v, ax); ax = fmaf(q2, pm2, ax);
                ax = fmaf(q3, o0, ax);   ax = fmaf(q4, o1, ax);
                ax = fmaf(q5, o2, ax);   ax = fmaf(q6, n0, ax);
                ax = fmaf(q7, n1, ax);   ax = fmaf(q8, n2, ax);
                cur[r][1] = fmaf(vR[r] * vC[1], frt[r][1] - ax, o1);
            }
            // c = 2
            {
                float ax = s0 * pm1v;
                ax = fmaf(q1, pm2, ax); ax = fmaf(q2, Rm1, ax);
                ax = fmaf(q3, o1, ax);  ax = fmaf(q4, o2, ax);
                ax = fmaf(q5, Rc, ax);  ax = fmaf(q6, n1, ax);
                ax = fmaf(q7, n2, ax);  ax = fmaf(q8, Rp, ax);
                cur[r][2] = fmaf(vR[r] * vC[2], frt[r][2] - ax, o2);
            }
            pm0 = o0; pm1v = o1; pm2 = o2;
            Lm1 = Lc; Rm1 = Rc; Lc = Lp; Rc = Rp;
        }
        __syncthreads();   // all halo reads done
        if (s < 9) {
            // write border cells (26)
            pwv[0] = cur[0][0]; pwv[1] = cur[0][1]; pwv[2] = cur[0][2];
            pwv[11 * TWP] = cur[11][0]; pwv[11 * TWP + 1] = cur[11][1];
            pwv[11 * TWP + 2] = cur[11][2];
#pragma unroll
            for (int r = 1; r < 11; ++r) {
                pwv[r * TWP] = cur[r][0];
                pwv[r * TWP + 2] = cur[r][2];
            }
        } else {
            // final sweep: publish ALL cells for the correction phase
#pragma unroll
            for (int r = 0; r < 12; ++r) {
                pwv[r * TWP] = cur[r][0];
                pwv[r * TWP + 1] = cur[r][1];
                pwv[r * TWP + 2] = cur[r][2];
            }
        }
        __syncthreads();   // writes visible
    }

    // ---- Phase D: remapped correction, exactly 1x MLP work ----
    // thread t -> output row orow = t/4 (0..63), column segment oseg = t%4
    // Pitch 97: bank = orow + 16*oseg + k + const (mod 32) -> 2 lanes/bank (free).
    const int orow = t >> 2;
    const int oseg = t & 3;
    const int Rl = HALO + orow;           // 16..79
    const int Cl0 = HALO + oseg * 16;     // 16,32,48,64
    const float* pw = sx + (Rl - 1) * TWP + (Cl0 - 1);   // single base + imm
    float w0[18], w1[18], w2[18];
#pragma unroll
    for (int k = 0; k < 18; ++k) {
        w0[k] = pw[k];
        w1[k] = pw[TWP + k];
        w2[k] = pw[2 * TWP + k];
    }
    const int gi = gy0 + orow;
    const int gjb = gx0 + oseg * 16;
    const float4* f4 = (const float4*)(fg + (size_t)gi * NN + gjb);
    const float4* l4 = (const float4*)(lfa + (size_t)b * NN * NN + (size_t)gi * NN + gjb);
    float fv[16], lv[16];
#pragma unroll
    for (int q = 0; q < 4; ++q) {
        float4 fq = f4[q], lq = l4[q];
        fv[q * 4] = fq.x; fv[q * 4 + 1] = fq.y; fv[q * 4 + 2] = fq.z; fv[q * 4 + 3] = fq.w;
        lv[q * 4] = lq.x; lv[q * 4 + 1] = lq.y; lv[q * 4 + 2] = lq.z; lv[q * 4 + 3] = lq.w;
    }
    float rv[16];
#pragma unroll
    for (int k = 0; k < 16; ++k) {
        float ax = ar0 * w0[k];
        ax = fmaf(ar1, w0[k + 1], ax); ax = fmaf(ar2, w0[k + 2], ax);
        ax = fmaf(ar3, w1[k], ax);     ax = fmaf(ar4, w1[k + 1], ax);
        ax = fmaf(ar5, w1[k + 2], ax); ax = fmaf(ar6, w2[k], ax);
        ax = fmaf(ar7, w2[k + 1], ax); ax = fmaf(ar8, w2[k + 2], ax);
        rv[k] = fv[k] - ax;
    }
    float acc[16];
#pragma unroll
    for (int k = 0; k < 16; ++k) acc[k] = 0.f;
    for (int hh = 0; hh < HID; ++hh) {
        float w1a = W1[2 * hh], w1b = W1[2 * hh + 1], bb = b1[hh], wo = W2[hh];
#pragma unroll
        for (int k = 0; k < 16; ++k) {
            float v = fmaf(w1a, lv[k], fmaf(w1b, rv[k], bb));
            float m = v * fmaf(GELU_K2, v * v, GELU_K1);
            float e = __builtin_amdgcn_exp2f(m);
            float g = v * __builtin_amdgcn_rcpf(1.0f + e);
            acc[k] = fmaf(wo, g, acc[k]);
        }
    }
    const float b2v = b2[0];
    float4* xo4 = (float4*)(xout + (size_t)b * NN * NN + (size_t)gi * NN + gjb);
#pragma unroll
    for (int q = 0; q < 4; ++q) {
        float4 ov;
        ov.x = w1[q * 4 + 1] + acc[q * 4] + b2v;
        ov.y = w1[q * 4 + 2] + acc[q * 4 + 1] + b2v;
        ov.z = w1[q * 4 + 3] + acc[q * 4 + 2] + b2v;
        ov.w = w1[q * 4 + 4] + acc[q * 4 + 3] + b2v;
        xo4[q] = ov;
    }
}

// ---------------------------------------------------------------------------
// Residual norm, vectorized strips of 4 cells (R10-proven, ~15 us).
// ---------------------------------------------------------------------------
__global__ __launch_bounds__(256) void resnorm_kernel(const float* __restrict__ xin,
                                                      const float* __restrict__ f,
                                                      const float* __restrict__ kernelA,
                                                      float* __restrict__ acc) {
    const int total_strips = BB * NN * (NN / 4);   // 1,048,576
    float rr = 0.f, f2 = 0.f;
    for (int p = blockIdx.x * 256 + threadIdx.x; p < total_strips;
         p += gridDim.x * 256) {
        int b = p >> 16;                  // NN*(NN/4) = 65536
        int rem = p & 65535;
        int i = rem >> 7;                 // 128 strips/row
        int js = (rem & 127) << 2;
        const float* a = kernelA + b * 9;
        const float* x = xin + (size_t)b * NN * NN;

        float4 up = {0,0,0,0}, mid, dn = {0,0,0,0};
        float upl = 0.f, upr = 0.f, midl = 0.f, midr = 0.f, dnl = 0.f, dnr = 0.f;
        const float* rowm = x + (size_t)i * NN + js;
        mid = *(const float4*)rowm;
        if (js > 0)       midl = rowm[-1];
        if (js + 4 < NN)  midr = rowm[4];
        if (i > 0) {
            const float* rowu = rowm - NN;
            up = *(const float4*)rowu;
            if (js > 0)      upl = rowu[-1];
            if (js + 4 < NN) upr = rowu[4];
        }
        if (i + 1 < NN) {
            const float* rowd = rowm + NN;
            dn = *(const float4*)rowd;
            if (js > 0)      dnl = rowd[-1];
            if (js + 4 < NN) dnr = rowd[4];
        }
        float u[6] = {upl, up.x, up.y, up.z, up.w, upr};
        float m[6] = {midl, mid.x, mid.y, mid.z, mid.w, midr};
        float d[6] = {dnl, dn.x, dn.y, dn.z, dn.w, dnr};
        float4 fq = *(const float4*)(f + (size_t)b * NN * NN + (size_t)i * NN + js);
        float fvv[4] = {fq.x, fq.y, fq.z, fq.w};
#pragma unroll
        for (int c = 0; c < 4; ++c) {
            float ax = a[0] * u[c];
            ax = fmaf(a[1], u[c + 1], ax); ax = fmaf(a[2], u[c + 2], ax);
            ax = fmaf(a[3], m[c], ax);     ax = fmaf(a[4], m[c + 1], ax);
            ax = fmaf(a[5], m[c + 2], ax); ax = fmaf(a[6], d[c], ax);
            ax = fmaf(a[7], d[c + 1], ax); ax = fmaf(a[8], d[c + 2], ax);
            float r = fvv[c] - ax;
            rr = fmaf(r, r, rr);
            f2 = fmaf(fvv[c], fvv[c], f2);
        }
    }
#pragma unroll
    for (int off = 32; off > 0; off >>= 1) {
        rr += __shfl_down(rr, off, 64);
        f2 += __shfl_down(f2, off, 64);
    }
    __shared__ float sr[4], sf[4];
    int wave = threadIdx.x >> 6;
    if ((threadIdx.x & 63) == 0) { sr[wave] = rr; sf[wave] = f2; }
    __syncthreads();
    if (threadIdx.x == 0) {
        atomicAdd(&acc[0], sr[0] + sr[1] + sr[2] + sr[3]);
        atomicAdd(&acc[1], sf[0] + sf[1] + sf[2] + sf[3]);
    }
}

__global__ void finalize_kernel(const float* __restrict__ acc, float* __restrict__ out) {
    out[0] = sqrtf(acc[0] / acc[1]);
}

// ---------------------------------------------------------------------------
extern "C" void kernel_launch(void* const* d_in, const int* in_sizes, int n_in,
                              void* d_out, int out_size, void* d_ws, size_t ws_size,
                              hipStream_t stream) {
    const float* f  = (const float*)d_in[0];
    const float* kA = (const float*)d_in[1];
    float*       u  = (float*)d_in[2];   // pristine zeros each launch; used as scratch
    const float* W1 = (const float*)d_in[3];
    const float* b1 = (const float*)d_in[4];
    const float* W2 = (const float*)d_in[5];
    const float* b2 = (const float*)d_in[6];
    float* out = (float*)d_out;

    char* ws = (char*)d_ws;
    float* acc = (float*)ws;                                     // 8 B
    float* xB  = (float*)(ws + 256);                             // 16 MiB
    float* lfa = (float*)(ws + 256 + (size_t)BB * NN * NN * 4);  // 16 MiB

    hipMemsetAsync(acc, 0, 2 * sizeof(float), stream);

    lfa_kernel<<<dim3(1, NN / 2, BB), 256, 0, stream>>>(kA, lfa);

    dim3 jblk(32, 8);
    dim3 jgrd(NN / OT, NN / OT, BB);

    // cycle 1 (x = 0, collapsed sweep 0), cycle 2, cycle 3
    fused_cycle<true><<<jgrd, jblk, 0, stream>>>(u, xB, f, kA, lfa, W1, b1, W2, b2);
    fused_cycle<false><<<jgrd, jblk, 0, stream>>>(xB, u, f, kA, lfa, W1, b1, W2, b2);
    fused_cycle<false><<<jgrd, jblk, 0, stream>>>(u, xB, f, kA, lfa, W1, b1, W2, b2);

    resnorm_kernel<<<2048, 256, 0, stream>>>(xB, f, kA, acc);
    finalize_kernel<<<1, 1, 0, stream>>>(acc, out);
}